// Round 2
// baseline (1584.312 us; speedup 1.0000x reference)
//
#include <hip/hip_runtime.h>
#include <hip/hip_bf16.h>
#include <stdint.h>

typedef __bf16 bf16_t;
typedef __bf16 bf16x8 __attribute__((ext_vector_type(8)));
typedef float f32x4 __attribute__((ext_vector_type(4)));

#define T_STEPS 64
#define BATCH   512
#define NTOKC   512
#define NINP    600
#define NHID    600
#define NBLK    6
#define BSZ     100
#define DK      64
#define ATTD    340
#define DC      32
#define KU_N    384     // 64 (k1) + 300 (u) + pad
#define OUT_KP  608     // NHID padded for dec GEMM K

// workspace layout (bytes), all 16B aligned
#define WS_KU     0u                 // 32768*384*4  = 50331648
#define WS_OUTB   50331648u          // 32768*608*2  = 39845888
#define WS_W1     90177536u          // 512*384*4    = 786432
#define WS_B1     90963968u          // 384*4        = 1536
#define WS_WVWX   90965504u          // 600*300*4    = 720000
#define WS_DECWT  91685504u          // 512*608*2    = 622592  (end ~92.3 MB)

// ---------------- prep kernels (tiny fp32 GEMMs) ----------------

__global__ void prep_wvwx(const float* __restrict__ Wv, const float* __restrict__ Wx,
                          float* __restrict__ WvWx) {
    int idx = blockIdx.x * 256 + threadIdx.x;
    if (idx >= NINP * 300) return;
    int i = idx / 300, c = idx % 300;
    float acc = 0.f;
    for (int a = 0; a < ATTD; a++) acc += Wv[i * ATTD + a] * Wx[a * 300 + c];
    WvWx[i * 300 + c] = acc;
}

__global__ void prep_w1(const float* __restrict__ encW, const float* __restrict__ Wk,
                        const float* __restrict__ WvWx, float* __restrict__ W1) {
    int idx = blockIdx.x * 256 + threadIdx.x;
    if (idx >= NTOKC * KU_N) return;
    int i = idx / KU_N, c = idx % KU_N;
    float acc = 0.f;
    if (c < DK) {
        for (int k = 0; k < NINP; k++) acc += encW[i * NINP + k] * Wk[k * DK + c];
    } else if (c < DK + 300) {
        int cc = c - DK;
        for (int k = 0; k < NINP; k++) acc += encW[i * NINP + k] * WvWx[k * 300 + cc];
    }
    W1[idx] = acc;
}

__global__ void prep_b1(const float* __restrict__ encB, const float* __restrict__ Wk,
                        const float* __restrict__ WvWx, float* __restrict__ b1) {
    int c = blockIdx.x * 256 + threadIdx.x;
    if (c >= KU_N) return;
    float acc = 0.f;
    if (c < DK) {
        for (int k = 0; k < NINP; k++) acc += encB[k] * Wk[k * DK + c];
    } else if (c < DK + 300) {
        int cc = c - DK;
        for (int k = 0; k < NINP; k++) acc += encB[k] * WvWx[k * 300 + cc];
    }
    b1[c] = acc;
}

__global__ void prep_decwt(const float* __restrict__ decW, bf16_t* __restrict__ decWT) {
    int idx = blockIdx.x * 256 + threadIdx.x;
    if (idx >= NTOKC * OUT_KP) return;
    int n = idx / OUT_KP, k = idx % OUT_KP;
    decWT[idx] = (k < NHID) ? (bf16_t)decW[k * NTOKC + n] : (bf16_t)0.f;
}

// ---------------- KU = input @ W1 + b1 (fp32; precision-critical) ----------------
// M=32768, K=512, N=384. BM=128 BN=64 BK=16, 256 thr, 8x4 per-thread tile.

__global__ __launch_bounds__(256) void ku_gemm(const float* __restrict__ A,
                                               const float* __restrict__ W1,
                                               const float* __restrict__ b1,
                                               float* __restrict__ KU) {
    __shared__ float As[16][128];
    __shared__ float Bs[16][64];
    const int tid = threadIdx.x;
    const int m0 = blockIdx.x * 128, n0 = blockIdx.y * 64;
    const int ty = tid >> 4, tx = tid & 15;
    const int bk = tid >> 6, bn = tid & 63;
    float acc[8][4] = {};
    for (int k0 = 0; k0 < NTOKC; k0 += 16) {
#pragma unroll
        for (int ii = 0; ii < 2; ii++) {
            int t2 = tid + ii * 256;
            int ar = t2 >> 2, ac4 = (t2 & 3) << 2;
            float4 raw = *(const float4*)(A + (size_t)(m0 + ar) * NTOKC + k0 + ac4);
            As[ac4 + 0][ar] = raw.x;
            As[ac4 + 1][ar] = raw.y;
            As[ac4 + 2][ar] = raw.z;
            As[ac4 + 3][ar] = raw.w;
        }
#pragma unroll
        for (int i = 0; i < 4; i++) {
            int kk = bk + (i << 2);
            Bs[kk][bn] = W1[(size_t)(k0 + kk) * KU_N + n0 + bn];
        }
        __syncthreads();
#pragma unroll
        for (int kk = 0; kk < 16; kk++) {
            float4 a0 = *(const float4*)&As[kk][ty * 8];
            float4 a1 = *(const float4*)&As[kk][ty * 8 + 4];
            float4 bv = *(const float4*)&Bs[kk][tx * 4];
            float av[8] = {a0.x, a0.y, a0.z, a0.w, a1.x, a1.y, a1.z, a1.w};
            float bw[4] = {bv.x, bv.y, bv.z, bv.w};
#pragma unroll
            for (int r = 0; r < 8; r++)
#pragma unroll
                for (int c = 0; c < 4; c++) acc[r][c] += av[r] * bw[c];
        }
        __syncthreads();
    }
#pragma unroll
    for (int r = 0; r < 8; r++) {
        int m = m0 + ty * 8 + r;
#pragma unroll
        for (int c = 0; c < 4; c++) {
            int n = n0 + tx * 4 + c;
            KU[(size_t)m * KU_N + n] = acc[r][c] + b1[n];
        }
    }
}

// ---------------- persistent scan: 1 WG per 2 batch elems, all 64 steps ----------------

__global__ __launch_bounds__(640) void scan_kernel(
    const float* __restrict__ hidden, const float* __restrict__ masks,
    const float* __restrict__ Wq, const float* __restrict__ Wh,
    const float* __restrict__ grub, const float* __restrict__ Wq2,
    const float* __restrict__ Wk2, const float* __restrict__ Wv2,
    const float* __restrict__ KU, bf16_t* __restrict__ outb,
    float* __restrict__ hT_out, float* __restrict__ bm_out) {
    __shared__ float h[2][NHID];
    __shared__ float u[2][300];
    __shared__ float k1s[2][DK];
    __shared__ float qb[2][NBLK][DK];
    __shared__ float p1s[2][8], bmv[2][8];
    __shared__ float hg[2][NBLK][300];   // hg, then hn in cols [0,100)
    __shared__ float qkv[2][NBLK][164];  // q2|k2|v2
    __shared__ float p2s[2][NBLK][8];

    const int tid = threadIdx.x;
    const int b0 = blockIdx.x * 2;

    for (int idx = tid; idx < 2 * NHID; idx += 640) {
        int b = idx / NHID, j = idx % NHID;
        h[b][j] = hidden[(size_t)(b0 + b) * NHID + j];
    }
    __syncthreads();

    for (int t = 0; t < T_STEPS; t++) {
        // phase 0: mask h, load k1/u
        {
            float mv0 = masks[t * BATCH + b0];
            float mv1 = masks[t * BATCH + b0 + 1];
            for (int idx = tid; idx < 2 * NHID; idx += 640) {
                int b = idx / NHID, j = idx % NHID;
                h[b][j] *= (b ? mv1 : mv0);
            }
            for (int idx = tid; idx < 2 * 364; idx += 640) {
                int b = idx / 364, c = idx % 364;
                float v = KU[(size_t)(t * BATCH + b0 + b) * KU_N + c];
                if (c < DK) k1s[b][c] = v; else u[b][c - DK] = v;
            }
        }
        __syncthreads();
        // phase 1: q = hb @ Wq  (768 dots of 100)
        for (int idx = tid; idx < 2 * NBLK * DK; idx += 640) {
            int b = idx / (NBLK * DK), r = idx % (NBLK * DK);
            int n = r / DK, d = r % DK;
            float acc = 0.f;
            const float* hp = &h[b][n * BSZ];
            for (int k = 0; k < BSZ; k += 4) {
                float4 h4 = *(const float4*)(hp + k);
                acc += h4.x * Wq[(k)*DK + d];
                acc += h4.y * Wq[(k + 1) * DK + d];
                acc += h4.z * Wq[(k + 2) * DK + d];
                acc += h4.w * Wq[(k + 3) * DK + d];
            }
            qb[b][n][d] = acc;
        }
        __syncthreads();
        // phase 2a: p1 = softmax([0,s])[1]  (s0 is exactly 0: src[0]=zeros)
        if (tid < 2 * NBLK) {
            int b = tid / NBLK, n = tid % NBLK;
            float s = 0.f;
            for (int d = 0; d < DK; d++) s += qb[b][n][d] * k1s[b][d];
            s *= 0.125f;
            float mx = fmaxf(s, 0.f);
            float e0 = expf(0.f - mx), e1 = expf(s - mx);
            p1s[b][n] = e1 / (e0 + e1);
        }
        __syncthreads();
        // phase 2b: stable top-4 mask (rank by p1, ties -> lower index, = lax.top_k)
        if (tid < 2 * NBLK) {
            int b = tid / NBLK, n = tid % NBLK;
            float pn = p1s[b][n];
            int cnt = 0;
            for (int j = 0; j < NBLK; j++) {
                float pj = p1s[b][j];
                if (pj > pn || (pj == pn && j < n)) cnt++;
            }
            float bm = (cnt < 4) ? 1.f : 0.f;
            bmv[b][n] = bm;
            bm_out[(size_t)(t * BATCH + b0 + b) * NBLK + n] = bm;
        }
        __syncthreads();
        // phase 3: hg = hb @ Wh  (outer product, 600 lanes own (b,c), 6 accs)
        for (int idx = tid; idx < 600; idx += 640) {
            int b = idx / 300, c = idx % 300;
            float acc[NBLK] = {};
            for (int k = 0; k < BSZ; k += 4) {
                float w0 = Wh[(k)*300 + c];
                float w1 = Wh[(k + 1) * 300 + c];
                float w2 = Wh[(k + 2) * 300 + c];
                float w3 = Wh[(k + 3) * 300 + c];
#pragma unroll
                for (int n = 0; n < NBLK; n++) {
                    float4 h4 = *(const float4*)&h[b][n * BSZ + k];
                    acc[n] += h4.x * w0 + h4.y * w1 + h4.z * w2 + h4.w * w3;
                }
            }
#pragma unroll
            for (int n = 0; n < NBLK; n++) hg[b][n][c] = acc[n];
        }
        __syncthreads();
        // phase 4: GRU -> hn (written into hg cols [0,100))
        for (int idx = tid; idx < 1200; idx += 640) {
            int b = idx / 600, r = idx % 600, n = r / BSZ, c = r % BSZ;
            float p1 = p1s[b][n];
            float xr = p1 * u[b][c] + grub[c];
            float xz = p1 * u[b][BSZ + c] + grub[BSZ + c];
            float xn = p1 * u[b][2 * BSZ + c] + grub[2 * BSZ + c];
            float hr = hg[b][n][c], hz = hg[b][n][BSZ + c], hnn = hg[b][n][2 * BSZ + c];
            float r_ = 1.f / (1.f + expf(-(xr + hr)));
            float z_ = 1.f / (1.f + expf(-(xz + hz)));
            float nn = tanhf(xn + r_ * hnn);
            float hold = h[b][n * BSZ + c];
            hg[b][n][c] = (1.f - z_) * nn + z_ * hold;
        }
        __syncthreads();
        // phase 5: q2|k2|v2 = hn @ [Wq2|Wk2|Wv2]
        for (int idx = tid; idx < 2 * 164; idx += 640) {
            int b = idx / 164, c = idx % 164;
            float acc[NBLK] = {};
            for (int k = 0; k < BSZ; k += 4) {
                float w0, w1, w2, w3;
                if (c < 32) {
                    w0 = Wq2[(k)*32 + c]; w1 = Wq2[(k + 1) * 32 + c];
                    w2 = Wq2[(k + 2) * 32 + c]; w3 = Wq2[(k + 3) * 32 + c];
                } else if (c < 64) {
                    int cc = c - 32;
                    w0 = Wk2[(k)*32 + cc]; w1 = Wk2[(k + 1) * 32 + cc];
                    w2 = Wk2[(k + 2) * 32 + cc]; w3 = Wk2[(k + 3) * 32 + cc];
                } else {
                    int cc = c - 64;
                    w0 = Wv2[(k)*100 + cc]; w1 = Wv2[(k + 1) * 100 + cc];
                    w2 = Wv2[(k + 2) * 100 + cc]; w3 = Wv2[(k + 3) * 100 + cc];
                }
#pragma unroll
                for (int n = 0; n < NBLK; n++) {
                    float4 h4 = *(const float4*)&hg[b][n][k];
                    acc[n] += h4.x * w0 + h4.y * w1 + h4.z * w2 + h4.w * w3;
                }
            }
#pragma unroll
            for (int n = 0; n < NBLK; n++) qkv[b][n][c] = acc[n];
        }
        __syncthreads();
        // phase 6a: p2 logits
        if (tid < 72) {
            int b = tid / 36, r = tid % 36, n = r / 6, m = r % 6;
            float e = 0.f;
            for (int d = 0; d < DC; d++) e += qkv[b][n][d] * qkv[b][m][32 + d];
            p2s[b][n][m] = e * 0.17677669529663687f;  // 1/sqrt(32)
        }
        __syncthreads();
        // phase 6b: softmax rows
        if (tid < 12) {
            int b = tid / 6, n = tid % 6;
            float mx = p2s[b][n][0];
            for (int m = 1; m < 6; m++) mx = fmaxf(mx, p2s[b][n][m]);
            float ev[6], sum = 0.f;
            for (int m = 0; m < 6; m++) { ev[m] = expf(p2s[b][n][m] - mx); sum += ev[m]; }
            for (int m = 0; m < 6; m++) p2s[b][n][m] = ev[m] / sum;
        }
        __syncthreads();
        // phase 7: hc = hn + p2@v2, blend by bmask, write h/outb/hT
        for (int idx = tid; idx < 1200; idx += 640) {
            int b = idx / 600, r = idx % 600, n = r / BSZ, c = r % BSZ;
            float acc = hg[b][n][c];
#pragma unroll
            for (int m = 0; m < 6; m++) acc += p2s[b][n][m] * qkv[b][m][64 + c];
            float hold = h[b][n * BSZ + c];
            float hnew = (bmv[b][n] != 0.f) ? acc : hold;
            h[b][n * BSZ + c] = hnew;
            size_t row = (size_t)(t * BATCH + b0 + b);
            outb[row * OUT_KP + n * BSZ + c] = (bf16_t)hnew;
            if (t == T_STEPS - 1) hT_out[(size_t)(b0 + b) * NHID + n * BSZ + c] = hnew;
        }
        for (int idx = tid; idx < 2 * 8; idx += 640) {
            int b = idx / 8, c = idx % 8;
            outb[(size_t)(t * BATCH + b0 + b) * OUT_KP + NHID + c] = (bf16_t)0.f;
        }
        __syncthreads();
    }
}

// ---------------- dec = outb @ decWT^T + dec_b (bf16 MFMA 16x16x32) ----------------
// M=32768 N=512 K=608. BM=128 BN=64 BK=32, 4 waves; wave: 2 m-tiles x 4 n-tiles.

__global__ __launch_bounds__(256) void dec_gemm(const bf16_t* __restrict__ Ag,
                                                const bf16_t* __restrict__ Bg,
                                                const float* __restrict__ bias,
                                                float* __restrict__ C) {
    __shared__ bf16_t As[128][32];
    __shared__ bf16_t Bs[64][32];
    const int tid = threadIdx.x;
    const int wave = tid >> 6, lane = tid & 63;
    const int m0 = blockIdx.x * 128, n0 = blockIdx.y * 64;
    f32x4 acc[2][4] = {};
    for (int k0 = 0; k0 < OUT_KP; k0 += 32) {
#pragma unroll
        for (int ii = 0; ii < 2; ii++) {
            int el = (tid + ii * 256) * 8;
            int row = el >> 5, col = el & 31;
            *(float4*)&As[row][col] = *(const float4*)(Ag + (size_t)(m0 + row) * OUT_KP + k0 + col);
        }
        {
            int el = tid * 8;
            int row = el >> 5, col = el & 31;
            *(float4*)&Bs[row][col] = *(const float4*)(Bg + (size_t)(n0 + row) * OUT_KP + k0 + col);
        }
        __syncthreads();
        const int fm = lane & 15, fq = (lane >> 4) * 8;
        bf16x8 a[2], b[4];
        a[0] = *(const bf16x8*)&As[wave * 32 + fm][fq];
        a[1] = *(const bf16x8*)&As[wave * 32 + 16 + fm][fq];
#pragma unroll
        for (int nt = 0; nt < 4; nt++) b[nt] = *(const bf16x8*)&Bs[nt * 16 + fm][fq];
#pragma unroll
        for (int mt = 0; mt < 2; mt++)
#pragma unroll
            for (int nt = 0; nt < 4; nt++)
                acc[mt][nt] = __builtin_amdgcn_mfma_f32_16x16x32_bf16(a[mt], b[nt], acc[mt][nt], 0, 0, 0);
        __syncthreads();
    }
    const int fm = lane & 15, fr = (lane >> 4) * 4;
#pragma unroll
    for (int mt = 0; mt < 2; mt++)
#pragma unroll
        for (int nt = 0; nt < 4; nt++) {
            int n = n0 + nt * 16 + fm;
            float bia = bias[n];
#pragma unroll
            for (int r = 0; r < 4; r++) {
                int m = m0 + wave * 32 + mt * 16 + fr + r;
                C[(size_t)m * NTOKC + n] = acc[mt][nt][r] + bia;
            }
        }
}

// ---------------- launch ----------------

extern "C" void kernel_launch(void* const* d_in, const int* in_sizes, int n_in,
                              void* d_out, int out_size, void* d_ws, size_t ws_size,
                              hipStream_t stream) {
    const float* input  = (const float*)d_in[0];
    const float* hidden = (const float*)d_in[1];
    const float* masks  = (const float*)d_in[2];
    const float* encW   = (const float*)d_in[3];
    const float* encB   = (const float*)d_in[4];
    const float* Wq     = (const float*)d_in[5];
    const float* Wk     = (const float*)d_in[6];
    const float* Wv     = (const float*)d_in[7];
    const float* Wx     = (const float*)d_in[8];
    const float* Wh     = (const float*)d_in[9];
    const float* grub   = (const float*)d_in[10];
    const float* Wq2    = (const float*)d_in[11];
    const float* Wk2    = (const float*)d_in[12];
    const float* Wv2    = (const float*)d_in[13];
    const float* decW   = (const float*)d_in[14];
    const float* decB   = (const float*)d_in[15];

    char* ws = (char*)d_ws;
    float*  KU    = (float*)(ws + WS_KU);
    bf16_t* outb  = (bf16_t*)(ws + WS_OUTB);
    float*  W1    = (float*)(ws + WS_W1);
    float*  b1    = (float*)(ws + WS_B1);
    float*  WvWx  = (float*)(ws + WS_WVWX);
    bf16_t* decWT = (bf16_t*)(ws + WS_DECWT);

    float* out_dec = (float*)d_out;
    float* out_hT  = out_dec + 16777216;   // T*B*NTOK
    float* out_bm  = out_dec + 17084416;   // + B*NHID

    prep_wvwx<<<(NINP * 300 + 255) / 256, 256, 0, stream>>>(Wv, Wx, WvWx);
    prep_w1<<<(NTOKC * KU_N + 255) / 256, 256, 0, stream>>>(encW, Wk, WvWx, W1);
    prep_b1<<<2, 256, 0, stream>>>(encB, Wk, WvWx, b1);
    prep_decwt<<<(NTOKC * OUT_KP + 255) / 256, 256, 0, stream>>>(decW, decWT);
    ku_gemm<<<dim3(256, 6), 256, 0, stream>>>(input, W1, b1, KU);
    scan_kernel<<<256, 640, 0, stream>>>(hidden, masks, Wq, Wh, grub, Wq2, Wk2, Wv2,
                                         KU, outb, out_hT, out_bm);
    dec_gemm<<<dim3(256, 8), 256, 0, stream>>>(outb, decWT, decB, out_dec);
}